// Round 9
// baseline (463.604 us; speedup 1.0000x reference)
//
#include <hip/hip_runtime.h>
#include <cstdint>
#include <cstddef>

typedef int i32x4 __attribute__((ext_vector_type(4)));

#define BM 256
#define BN 256
#define BK 64   // bytes of K per tile; one mfma_i32_16x16x64_i8 covers the whole tile-K

__device__ __forceinline__ void load16_to_lds(const void* g, void* l) {
  __builtin_amdgcn_global_load_lds(
      (const __attribute__((address_space(1))) void*)g,
      (__attribute__((address_space(3))) void*)l,
      16, 0, 0);
}

// Fused input quantization, one WAVE per row, no barriers / no LDS (round-6, verified).
__global__ __launch_bounds__(256) void quant_xw(const float* __restrict__ x,
                                                char* __restrict__ xq,
                                                float* __restrict__ sx,
                                                const int* __restrict__ w,
                                                char* __restrict__ wq,
                                                int M, int K) {
  const int wid = blockIdx.x * 4 + (threadIdx.x >> 6);
  const int l   = threadIdx.x & 63;
  if (wid < M) {
    const float4* xr = (const float4*)(x + (size_t)wid * K);
    float4 v[16];
    float amax = 0.f;
#pragma unroll
    for (int j = 0; j < 16; ++j) {
      v[j] = xr[j * 64 + l];
      amax = fmaxf(amax, fmaxf(fmaxf(fabsf(v[j].x), fabsf(v[j].y)),
                               fmaxf(fabsf(v[j].z), fabsf(v[j].w))));
    }
#pragma unroll
    for (int off = 32; off; off >>= 1)
      amax = fmaxf(amax, __shfl_xor(amax, off));
    amax = fmaxf(amax, 1e-20f);

    const float s = 127.0f / amax;
    int* outw = (int*)(xq + (size_t)wid * K);
#pragma unroll
    for (int j = 0; j < 16; ++j) {
      int q0 = __float2int_rn(v[j].x * s);
      int q1 = __float2int_rn(v[j].y * s);
      int q2 = __float2int_rn(v[j].z * s);
      int q3 = __float2int_rn(v[j].w * s);
      outw[j * 64 + l] = (q0 & 0xff) | ((q1 & 0xff) << 8) |
                         ((q2 & 0xff) << 16) | ((q3 & 0xff) << 24);
    }
    if (l == 0) sx[wid] = amax * (1.0f / 127.0f);
  } else {
    const int r = wid - M;
    const int4* wr = (const int4*)(w + (size_t)r * K);
    int* outw = (int*)(wq + (size_t)r * K);
#pragma unroll
    for (int j = 0; j < 16; ++j) {
      int4 a = wr[j * 64 + l];
      outw[j * 64 + l] = (a.x & 0xff) | ((a.y & 0xff) << 8) |
                         ((a.z & 0xff) << 16) | ((a.w & 0xff) << 24);
    }
  }
}

// C[m][n] = sum_k A[m][k]*Bw[n][k] (int8 -> int32); out = C*sx[m]*sw[n] + bias[n].
// 256x256 tile, 512 thr (8 waves: 2M x 4N -> 128x64 per wave), BK=64B,
// mfma_i32_16x16x64_i8, 3 LDS buffers (96 KiB), depth-2 prefetch.
// OVERLAPPED schedule: every phase's ds_reads are issued INSIDE the previous
// phase's MFMA region, so the (per-CU, shared) LDS unit serves reads while the
// matrix pipe runs. Barrier cadence identical to the verified round-1 kernel.
//   P0(t): stage A(t+2); bar; lgkm0[R1(t)]; { issue a4-7(t); 16 MFMA a0-3 x b0-3 }; bar
//   P1(t): stage B(t+2); vmcnt(4) [retire t+1's pair -> buf(t+1) readable]; bar;
//          lgkm0[a4-7]; { issue R1(t+1)=a0-3,b0-3 of buf(t+1); 16 MFMA a4-7 x b0-3 }; bar
// Register ping-pong via unroll-2 (no rotation movs).
// WAR: DMA into (t+2)%3==(t-1)%3 — all reads of buf(t-1) (R1(t-1) drained at P0(t-1)
// lgkm0, a4-7(t-1) drained at P1(t-1) lgkm0) complete before tile-end bar(t-1),
// which precedes the DMA. vmcnt FIFO: outstanding before P1(t)'s wait =
// {A(t+1),B(t+1),A(t+2),B(t+2)} (2 each) -> vmcnt(4) retires exactly t+1's pair.
// LDS swizzle (verified conflict-free): 16B chunk (row r, chunk c) at byte
// r*64 + ((c^((r>>1)&3))<<4); pre-swizzled global source, linear DMA dst.
__global__ __launch_bounds__(512) void gemm_i8_bt(const char* __restrict__ A,
                                                  const char* __restrict__ Bw,
                                                  const float* __restrict__ sx,
                                                  const float* __restrict__ sw,
                                                  const float* __restrict__ bias,
                                                  float* __restrict__ out,
                                                  int M, int N, int K) {
  __shared__ __align__(16) char As[3][BM * BK];   // 3 x 16 KiB
  __shared__ __align__(16) char Bs[3][BN * BK];   // 3 x 16 KiB  (96 KiB total)

  const int tid  = threadIdx.x;
  const int wave = tid >> 6;
  const int lane = tid & 63;
  const int wm   = wave >> 2;      // 0..1 -> 128-row half
  const int wn   = wave & 3;       // 0..3 -> 64-col quarter

  // XCD-aware bijective block swizzle (nwg = 512, divisible by 8)
  const int gx   = N / BN;                              // 16
  const int nwg  = gx * (M / BM);                       // 512
  const int orig = blockIdx.y * gx + blockIdx.x;
  const int wg   = (orig & 7) * (nwg >> 3) + (orig >> 3);
  const int bn   = wg % gx;
  const int bm   = wg / gx;

  i32x4 acc[8][4] = {};

  // Staging: thread stages chunks q=tid and q=tid+512 of each tile.
  const int rowT = tid >> 2;
  const int jg   = ((tid & 3) ^ ((tid >> 3) & 3)) << 4;
  const char* Ag1 = A  + (size_t)(bm * BM + rowT) * K + jg;
  const char* Ag2 = Ag1 + (size_t)128 * K;
  const char* Bg1 = Bw + (size_t)(bn * BN + rowT) * K + jg;
  const char* Bg2 = Bg1 + (size_t)128 * K;

  const int ldsO1 = wave << 10;             // chunk q=tid      -> byte tid*16
  const int ldsO2 = 8192 + (wave << 10);    // chunk q=tid+512

  // Fragment read offsets: row R, k-chunk j=lane>>4 at byte R*64 + ((j^((R>>1)&3))<<4).
  const int fr  = lane & 15;
  const int swz = (((lane >> 4) ^ ((fr >> 1) & 3)) << 4);
  int offA[8], offB[4];
#pragma unroll
  for (int m = 0; m < 8; ++m) offA[m] = (wm * 128 + m * 16 + fr) * 64 + swz;
#pragma unroll
  for (int n = 0; n < 4; ++n) offB[n] = (wn * 64 + n * 16 + fr) * 64 + swz;

  const int NT = K / BK;    // 64 (even -> unroll-2 safe)

  // Prologue: stage tiles 0,1; confirm tile 0 (keep tile 1's 4 loads in flight).
  load16_to_lds(Ag1,      &As[0][ldsO1]);
  load16_to_lds(Ag2,      &As[0][ldsO2]);
  load16_to_lds(Bg1,      &Bs[0][ldsO1]);
  load16_to_lds(Bg2,      &Bs[0][ldsO2]);
  load16_to_lds(Ag1 + BK, &As[1][ldsO1]);
  load16_to_lds(Ag2 + BK, &As[1][ldsO2]);
  load16_to_lds(Bg1 + BK, &Bs[1][ldsO1]);
  load16_to_lds(Bg2 + BK, &Bs[1][ldsO2]);
  asm volatile("s_waitcnt vmcnt(4)" ::: "memory");
  __builtin_amdgcn_s_barrier();

  // R1(0): a0-3,b0-3 of tile 0 (waited at first P0's lgkm0).
  i32x4 xa[4], xb[4], ya[4], yb[4];
#pragma unroll
  for (int m = 0; m < 4; ++m) xa[m] = *(const i32x4*)&As[0][offA[m]];
#pragma unroll
  for (int n = 0; n < 4; ++n) xb[n] = *(const i32x4*)&Bs[0][offB[n]];

#define TILE_STEP(T, CA, CB, NA, NB)                                               \
  {                                                                                \
    const int    buf = (T) % 3;                                                    \
    const int    nbf = ((T) + 2) % 3;                                              \
    const int    nxf = ((T) + 1) % 3;                                              \
    const size_t ko  = (size_t)((T) + 2) * BK;                                     \
    const bool   pf  = (T) + 2 < NT;                                               \
    const bool   rd  = (T) + 1 < NT;                                               \
    /* ---- P0 ---- */                                                             \
    if (pf) {                                                                      \
      load16_to_lds(Ag1 + ko, &As[nbf][ldsO1]);                                    \
      load16_to_lds(Ag2 + ko, &As[nbf][ldsO2]);                                    \
    }                                                                              \
    __builtin_amdgcn_s_barrier();                                                  \
    asm volatile("s_waitcnt lgkmcnt(0)" ::: "memory");                             \
    __builtin_amdgcn_sched_barrier(0);                                             \
    __builtin_amdgcn_s_setprio(1);                                                 \
    i32x4 a4 = *(const i32x4*)&As[buf][offA[4]];                                   \
    i32x4 a5 = *(const i32x4*)&As[buf][offA[5]];                                   \
    i32x4 a6 = *(const i32x4*)&As[buf][offA[6]];                                   \
    i32x4 a7 = *(const i32x4*)&As[buf][offA[7]];                                   \
    acc[0][0] = __builtin_amdgcn_mfma_i32_16x16x64_i8(CA[0], CB[0], acc[0][0], 0, 0, 0); \
    acc[0][1] = __builtin_amdgcn_mfma_i32_16x16x64_i8(CA[0], CB[1], acc[0][1], 0, 0, 0); \
    acc[0][2] = __builtin_amdgcn_mfma_i32_16x16x64_i8(CA[0], CB[2], acc[0][2], 0, 0, 0); \
    acc[0][3] = __builtin_amdgcn_mfma_i32_16x16x64_i8(CA[0], CB[3], acc[0][3], 0, 0, 0); \
    acc[1][0] = __builtin_amdgcn_mfma_i32_16x16x64_i8(CA[1], CB[0], acc[1][0], 0, 0, 0); \
    acc[1][1] = __builtin_amdgcn_mfma_i32_16x16x64_i8(CA[1], CB[1], acc[1][1], 0, 0, 0); \
    acc[1][2] = __builtin_amdgcn_mfma_i32_16x16x64_i8(CA[1], CB[2], acc[1][2], 0, 0, 0); \
    acc[1][3] = __builtin_amdgcn_mfma_i32_16x16x64_i8(CA[1], CB[3], acc[1][3], 0, 0, 0); \
    acc[2][0] = __builtin_amdgcn_mfma_i32_16x16x64_i8(CA[2], CB[0], acc[2][0], 0, 0, 0); \
    acc[2][1] = __builtin_amdgcn_mfma_i32_16x16x64_i8(CA[2], CB[1], acc[2][1], 0, 0, 0); \
    acc[2][2] = __builtin_amdgcn_mfma_i32_16x16x64_i8(CA[2], CB[2], acc[2][2], 0, 0, 0); \
    acc[2][3] = __builtin_amdgcn_mfma_i32_16x16x64_i8(CA[2], CB[3], acc[2][3], 0, 0, 0); \
    acc[3][0] = __builtin_amdgcn_mfma_i32_16x16x64_i8(CA[3], CB[0], acc[3][0], 0, 0, 0); \
    acc[3][1] = __builtin_amdgcn_mfma_i32_16x16x64_i8(CA[3], CB[1], acc[3][1], 0, 0, 0); \
    acc[3][2] = __builtin_amdgcn_mfma_i32_16x16x64_i8(CA[3], CB[2], acc[3][2], 0, 0, 0); \
    acc[3][3] = __builtin_amdgcn_mfma_i32_16x16x64_i8(CA[3], CB[3], acc[3][3], 0, 0, 0); \
    __builtin_amdgcn_s_setprio(0);                                                 \
    __builtin_amdgcn_sched_barrier(0);                                             \
    __builtin_amdgcn_s_barrier();                                                  \
    /* ---- P1 ---- */                                                             \
    if (pf) {                                                                      \
      load16_to_lds(Bg1 + ko, &Bs[nbf][ldsO1]);                                    \
      load16_to_lds(Bg2 + ko, &Bs[nbf][ldsO2]);                                    \
    }                                                                              \
    if (pf)      { asm volatile("s_waitcnt vmcnt(4)" ::: "memory"); }              \
    else if (rd) { asm volatile("s_waitcnt vmcnt(0)" ::: "memory"); }              \
    __builtin_amdgcn_s_barrier();                                                  \
    asm volatile("s_waitcnt lgkmcnt(0)" ::: "memory");                             \
    __builtin_amdgcn_sched_barrier(0);                                             \
    __builtin_amdgcn_s_setprio(1);                                                 \
    if (rd) {                                                                      \
      NA[0] = *(const i32x4*)&As[nxf][offA[0]];                                    \
      NA[1] = *(const i32x4*)&As[nxf][offA[1]];                                    \
      NA[2] = *(const i32x4*)&As[nxf][offA[2]];                                    \
      NA[3] = *(const i32x4*)&As[nxf][offA[3]];                                    \
      NB[0] = *(const i32x4*)&Bs[nxf][offB[0]];                                    \
      NB[1] = *(const i32x4*)&Bs[nxf][offB[1]];                                    \
      NB[2] = *(const i32x4*)&Bs[nxf][offB[2]];                                    \
      NB[3] = *(const i32x4*)&Bs[nxf][offB[3]];                                    \
    }                                                                              \
    acc[4][0] = __builtin_amdgcn_mfma_i32_16x16x64_i8(a4, CB[0], acc[4][0], 0, 0, 0); \
    acc[4][1] = __builtin_amdgcn_mfma_i32_16x16x64_i8(a4, CB[1], acc[4][1], 0, 0, 0); \
    acc[4][2] = __builtin_amdgcn_mfma_i32_16x16x64_i8(a4, CB[2], acc[4][2], 0, 0, 0); \
    acc[4][3] = __builtin_amdgcn_mfma_i32_16x16x64_i8(a4, CB[3], acc[4][3], 0, 0, 0); \
    acc[5][0] = __builtin_amdgcn_mfma_i32_16x16x64_i8(a5, CB[0], acc[5][0], 0, 0, 0); \
    acc[5][1] = __builtin_amdgcn_mfma_i32_16x16x64_i8(a5, CB[1], acc[5][1], 0, 0, 0); \
    acc[5][2] = __builtin_amdgcn_mfma_i32_16x16x64_i8(a5, CB[2], acc[5][2], 0, 0, 0); \
    acc[5][3] = __builtin_amdgcn_mfma_i32_16x16x64_i8(a5, CB[3], acc[5][3], 0, 0, 0); \
    acc[6][0] = __builtin_amdgcn_mfma_i32_16x16x64_i8(a6, CB[0], acc[6][0], 0, 0, 0); \
    acc[6][1] = __builtin_amdgcn_mfma_i32_16x16x64_i8(a6, CB[1], acc[6][1], 0, 0, 0); \
    acc[6][2] = __builtin_amdgcn_mfma_i32_16x16x64_i8(a6, CB[2], acc[6][2], 0, 0, 0); \
    acc[6][3] = __builtin_amdgcn_mfma_i32_16x16x64_i8(a6, CB[3], acc[6][3], 0, 0, 0); \
    acc[7][0] = __builtin_amdgcn_mfma_i32_16x16x64_i8(a7, CB[0], acc[7][0], 0, 0, 0); \
    acc[7][1] = __builtin_amdgcn_mfma_i32_16x16x64_i8(a7, CB[1], acc[7][1], 0, 0, 0); \
    acc[7][2] = __builtin_amdgcn_mfma_i32_16x16x64_i8(a7, CB[2], acc[7][2], 0, 0, 0); \
    acc[7][3] = __builtin_amdgcn_mfma_i32_16x16x64_i8(a7, CB[3], acc[7][3], 0, 0, 0); \
    __builtin_amdgcn_s_setprio(0);                                                 \
    __builtin_amdgcn_sched_barrier(0);                                             \
    __builtin_amdgcn_s_barrier();                                                  \
  }

  for (int t = 0; t < NT; t += 2) {
    TILE_STEP(t,     xa, xb, ya, yb);
    TILE_STEP(t + 1, ya, yb, xa, xb);
  }
#undef TILE_STEP

  // Epilogue. C/D layout (dtype-independent): col = lane&15, row = (lane>>4)*4 + reg.
  const int colc = lane & 15;
  const int rq   = (lane >> 4) << 2;
  float sxv[8][4];
#pragma unroll
  for (int m = 0; m < 8; ++m) {
    const int row0 = bm * BM + wm * 128 + m * 16 + rq;
#pragma unroll
    for (int r = 0; r < 4; ++r) sxv[m][r] = sx[row0 + r];
  }
#pragma unroll
  for (int n = 0; n < 4; ++n) {
    const int col = bn * BN + wn * 64 + n * 16 + colc;
    const float sc = sw[col];
    const float bi = bias[col];
#pragma unroll
    for (int m = 0; m < 8; ++m) {
      const int row0 = bm * BM + wm * 128 + m * 16 + rq;
#pragma unroll
      for (int r = 0; r < 4; ++r)
        out[(size_t)(row0 + r) * N + col] = (float)acc[m][n][r] * (sxv[m][r] * sc) + bi;
    }
  }
}

extern "C" void kernel_launch(void* const* d_in, const int* in_sizes, int n_in,
                              void* d_out, int out_size, void* d_ws, size_t ws_size,
                              hipStream_t stream) {
  const float* x     = (const float*)d_in[0];
  const int*   w     = (const int*)d_in[1];
  const float* scale = (const float*)d_in[2];
  const float* bias  = (const float*)d_in[3];
  float*       out   = (float*)d_out;

  const int N = in_sizes[3];          // D_OUT = 4096
  const int K = in_sizes[1] / N;      // D_IN  = 4096
  const int M = in_sizes[0] / K;      // B*S   = 8192

  char*  xq = (char*)d_ws;                       // M*K i8  = 32 MiB
  char*  wq = xq + (size_t)M * K;                // N*K i8  = 16 MiB
  float* sx = (float*)(wq + (size_t)N * K);      // M floats

  // Wave-tasks: M x-rows + N w-rows; 4 waves per 256-thr block.
  const unsigned nwaves = (unsigned)(M + N);
  quant_xw<<<dim3(nwaves / 4), dim3(256), 0, stream>>>(x, xq, sx, w, wq, M, K);

  gemm_i8_bt<<<dim3(N / BN, M / BM), dim3(512), 0, stream>>>(xq, wq, sx, scale, bias, out, M, N, K);
}